// Round 18
// baseline (711.463 us; speedup 1.0000x reference)
//
#include <hip/hip_runtime.h>

#define H 181
#define T_LEN 1024
#define BB 4             // batch rows per block
#define NBLK 256         // 256 * 4 = 1024; one block per CU (LDS-pinned)
#define NTHR 512         // R23: 8 waves, 2 per SIMD, 256-reg cap
#define KT3 3            // k-tiles of 64 -> 192 >= 181
#define FRAGB 1024       // bytes per kt fragment (64 lanes x 16 B)
#define PST 192          // unit stride (wsc, FC)
#define XSTR 1027        // x_s stride (odd -> broadcast reads conflict-free)

typedef __attribute__((ext_vector_type(4))) int intx4;

#define LOG2E 1.4426950408889634f
// Schraudolph exp2 (balanced sawtooth, |rel err| <= ~3%), clamped
#define SCH_C  1064992506.0f
#define SCH_LO 897220352.0f
#define SCH_HI 1182433024.0f

__device__ __forceinline__ float exp2_fast(float g) {
    float s = fmaf(g, 8388608.0f, SCH_C);
    s = fminf(fmaxf(s, SCH_LO), SCH_HI);
    return __uint_as_float((unsigned)s);
}
__device__ __forceinline__ float rcpf(float x)   { return __builtin_amdgcn_rcpf(x); }
__device__ __forceinline__ float exp2hw(float x) { return __builtin_amdgcn_exp2f(x); }

// R25 == R23 resubmit (broker timeout 2x; never measured).
// R23: 8-wave restructure (pre-committed fallback after R20/R21/R22 all
// failed to de-spill: VGPR 84 + WRITE ~27MB across array/named/waves_per_eu/
// asm-pin variants; R22's pin added writeback traffic with dur flat ->
// reloads may be latency-hidden, but only a spill-free build adjudicates).
// NTHR=512, launch_bounds(512,2) -> 256-reg budget (R18-proven residency
// regime). Waves 0-3 own tiles {jt, 8+jt}; waves 4-7 own tile {jt}:
// per SIMD = one 2-tile + one 1-tile wave = 27 MFMA/step, identical issue
// load to the 670us 12-wave baseline. bf reads 36->24/CU/step; barrier
// 12->8 waves. "two" branch is wave-uniform (no exec divergence).
// Adjudication: WRITE ~40KB + dur 560-620 = spill was real cost;
// WRITE ~40KB + dur ~670 = spill exonerated -> attack VALU chain next;
// WRITE ~27MB = pathology beyond source -> attack VALU anyway;
// dur > 700 = 8-wave worse -> revert R19 structure.
__device__ __forceinline__ float row_scale(const float* wrow, bool mv) {
    float rm = 0.0f;
    if (mv) for (int k = 0; k < H; ++k) rm = fmaxf(rm, fabsf(wrow[k]));
    return (rm > 1e-30f) ? rm * (1.0f / 127.0f) : 1.0f;
}

__device__ __forceinline__ intx4 build_frag(const float* wrow, float invs,
                                            bool mv, int kt, int q) {
    intx4 frag;
    #pragma unroll
    for (int w = 0; w < 4; ++w) {
        int dw = 0;
        #pragma unroll
        for (int e = 0; e < 4; ++e) {
            int k = kt * 64 + q * 16 + w * 4 + e;
            float v = (mv && k < H) ? wrow[k] * invs : 0.0f;
            v = fminf(fmaxf(rintf(v), -127.0f), 127.0f);
            int iv = (int)v;
            dw |= (iv & 255) << (8 * e);
        }
        frag[w] = dw;
    }
    return frag;
}

__launch_bounds__(NTHR, 2)
__global__ void gru_i8(const float* __restrict__ x,
                       const float* __restrict__ w_ih,
                       const float* __restrict__ w_hh,
                       const float* __restrict__ b_ih,
                       const float* __restrict__ b_hh,
                       const float* __restrict__ w_fc,
                       const float* __restrict__ b_fc,
                       float* __restrict__ out) {
    __shared__ __align__(16) char  hfr_s[2 * KT3 * FRAGB];  // 6 KB i8 h dbuf
    __shared__ __align__(16) float x_s[BB * XSTR];          // 16 KB x; reused for FC
    __shared__ float wsc_s[3 * PST];                        // w_hh row scales
    __shared__ volatile char pad_s[57344];                  // total > 80 KB: pin 1 block/CU

    const int tid  = threadIdx.x;
    const int jt   = tid >> 6;          // wave 0..7
    const int lane = tid & 63;
    const int col  = lane & 15;
    const int q    = lane >> 4;
    const int b0   = blockIdx.x * BB;
    const bool two = (jt < 4);          // waves 0-3 own a second tile (8+jt)
    if (tid == 0) pad_s[0] = 0;

    // ---- A-fragments: tile ttA = jt (units jt*16..+15, all < H) ----
    const int  muA = jt * 16 + col;
    const bool mvA = (muA < H);
    const float* wrAR = w_hh + (size_t)(0 * H + (mvA ? muA : 0)) * H;
    const float* wrAZ = w_hh + (size_t)(1 * H + (mvA ? muA : 0)) * H;
    const float* wrAN = w_hh + (size_t)(2 * H + (mvA ? muA : 0)) * H;
    const float sAR = row_scale(wrAR, mvA);
    const float sAZ = row_scale(wrAZ, mvA);
    const float sAN = row_scale(wrAN, mvA);
    const intx4 aAR0 = build_frag(wrAR, 1.0f / sAR, mvA, 0, q);
    const intx4 aAR1 = build_frag(wrAR, 1.0f / sAR, mvA, 1, q);
    const intx4 aAR2 = build_frag(wrAR, 1.0f / sAR, mvA, 2, q);
    const intx4 aAZ0 = build_frag(wrAZ, 1.0f / sAZ, mvA, 0, q);
    const intx4 aAZ1 = build_frag(wrAZ, 1.0f / sAZ, mvA, 1, q);
    const intx4 aAZ2 = build_frag(wrAZ, 1.0f / sAZ, mvA, 2, q);
    const intx4 aAN0 = build_frag(wrAN, 1.0f / sAN, mvA, 0, q);
    const intx4 aAN1 = build_frag(wrAN, 1.0f / sAN, mvA, 1, q);
    const intx4 aAN2 = build_frag(wrAN, 1.0f / sAN, mvA, 2, q);
    if (q == 0) {
        wsc_s[0 * PST + muA] = sAR;
        wsc_s[1 * PST + muA] = sAZ;
        wsc_s[2 * PST + muA] = sAN;
    }

    // ---- B-fragments: tile ttB = 8+jt (waves 0-3 only; units 128..191) ----
    const int  muB = (8 + jt) * 16 + col;          // <= 191 < PST
    const bool mvB = two && (muB < H);
    intx4 aBR0 = {0,0,0,0}, aBR1 = {0,0,0,0}, aBR2 = {0,0,0,0};
    intx4 aBZ0 = {0,0,0,0}, aBZ1 = {0,0,0,0}, aBZ2 = {0,0,0,0};
    intx4 aBN0 = {0,0,0,0}, aBN1 = {0,0,0,0}, aBN2 = {0,0,0,0};
    if (two) {
        const float* wrBR = w_hh + (size_t)(0 * H + (mvB ? muB : 0)) * H;
        const float* wrBZ = w_hh + (size_t)(1 * H + (mvB ? muB : 0)) * H;
        const float* wrBN = w_hh + (size_t)(2 * H + (mvB ? muB : 0)) * H;
        const float sBR = row_scale(wrBR, mvB);
        const float sBZ = row_scale(wrBZ, mvB);
        const float sBN = row_scale(wrBN, mvB);
        aBR0 = build_frag(wrBR, 1.0f / sBR, mvB, 0, q);
        aBR1 = build_frag(wrBR, 1.0f / sBR, mvB, 1, q);
        aBR2 = build_frag(wrBR, 1.0f / sBR, mvB, 2, q);
        aBZ0 = build_frag(wrBZ, 1.0f / sBZ, mvB, 0, q);
        aBZ1 = build_frag(wrBZ, 1.0f / sBZ, mvB, 1, q);
        aBZ2 = build_frag(wrBZ, 1.0f / sBZ, mvB, 2, q);
        aBN0 = build_frag(wrBN, 1.0f / sBN, mvB, 0, q);
        aBN1 = build_frag(wrBN, 1.0f / sBN, mvB, 1, q);
        aBN2 = build_frag(wrBN, 1.0f / sBN, mvB, 2, q);
        if (q == 0) {
            wsc_s[0 * PST + muB] = sBR;
            wsc_s[1 * PST + muB] = sBZ;
            wsc_s[2 * PST + muB] = sBN;
        }
    }

    // ---- stage x (stride 1027); zero h frag buffers ----
    for (int i = tid; i < BB * T_LEN; i += NTHR) {
        int bb = i >> 10, t = i & 1023;
        x_s[bb * XSTR + t] = x[(size_t)b0 * T_LEN + i];
    }
    {
        int* hz = (int*)hfr_s;
        for (int i = tid; i < 2 * KT3 * FRAGB / 4; i += NTHR) hz[i] = 0;
    }
    __syncthreads();   // wsc_s ready

    // ---- dense per-lane identity (one (unit,batch) pair per lane/tile) ----
    const int  rr4 = (col >> 2) & 3;
    const int  b   = col & 3;
    const int  uA  = jt * 16 + q * 4 + rr4;          // 0..127, always valid
    const int  uB  = (8 + jt) * 16 + q * 4 + rr4;    // 128..191 (two only)
    const bool jvA = (uA < H);
    const bool jvB = two && (uB < H);
    const float dqRA = -LOG2E * wsc_s[0 * PST + uA] * (1.0f / 127.0f);
    const float dqZA = -LOG2E * wsc_s[1 * PST + uA] * (1.0f / 127.0f);
    const float dqNA =  2.0f * LOG2E * wsc_s[2 * PST + uA] * (1.0f / 127.0f);
    const float baseRA = jvA ? -LOG2E * (b_ih[uA] + b_hh[uA])         : 0.0f;
    const float baseZA = jvA ? -LOG2E * (b_ih[H + uA] + b_hh[H + uA]) : 0.0f;
    const float baseNA = jvA ?  2.0f * LOG2E * b_hh[2 * H + uA]       : 0.0f;
    const float wrSA = jvA ? -LOG2E * w_ih[uA]                : 0.0f;
    const float wzSA = jvA ? -LOG2E * w_ih[H + uA]            : 0.0f;
    const float wnSA = jvA ?  2.0f * LOG2E * w_ih[2 * H + uA] : 0.0f;
    const float bnIA = jvA ?  2.0f * LOG2E * b_ih[2 * H + uA] : 0.0f;
    const float dqRB = -LOG2E * wsc_s[0 * PST + uB] * (1.0f / 127.0f);
    const float dqZB = -LOG2E * wsc_s[1 * PST + uB] * (1.0f / 127.0f);
    const float dqNB =  2.0f * LOG2E * wsc_s[2 * PST + uB] * (1.0f / 127.0f);
    const float baseRB = jvB ? -LOG2E * (b_ih[uB] + b_hh[uB])         : 0.0f;
    const float baseZB = jvB ? -LOG2E * (b_ih[H + uB] + b_hh[H + uB]) : 0.0f;
    const float baseNB = jvB ?  2.0f * LOG2E * b_hh[2 * H + uB]       : 0.0f;
    const float wrSB = jvB ? -LOG2E * w_ih[uB]                : 0.0f;
    const float wzSB = jvB ? -LOG2E * w_ih[H + uB]            : 0.0f;
    const float wnSB = jvB ?  2.0f * LOG2E * w_ih[2 * H + uB] : 0.0f;
    const float bnIB = jvB ?  2.0f * LOG2E * b_ih[2 * H + uB] : 0.0f;
    // per-lane byte slots: tile tt -> (tt>>2)*FRAGB + ((tt&3)*16+b)*16 + q*4 + rr4
    const int woffA = (jt >> 2) * FRAGB + (((jt & 3) * 16 + b) * 16) + q * 4 + rr4;
    const int woffB = ((8 + jt) >> 2) * FRAGB + ((((8 + jt) & 3) * 16 + b) * 16) + q * 4 + rr4;
    const int rbase = lane * 16;

    float hA = 0.0f, hB = 0.0f;

// Gate math + quant + b8 write for one tile (R20 numerics, bit-identical).
#define GATES(vR_, vZ_, vN_, dqR_, dqZ_, dqN_, baseR_, baseZ_, baseN_,       \
              wrS_, wzS_, wnS_, bnI_, h_, wb, woff_) do {                     \
    float pR = fmaf((float)(vR_), dqR_, baseR_);                              \
    float pZ = fmaf((float)(vZ_), dqZ_, baseZ_);                              \
    float pN = fmaf((float)(vN_), dqN_, baseN_);                              \
    float er = exp2_fast(fmaf(xv, wrS_, pR));                                 \
    float ez = exp2hw(fminf(fmaf(xv, wzS_, pZ), 14.0f));                      \
    float dR = 1.0f + er, dZ = 1.0f + ez;                                     \
    float qq = rcpf(dR * dZ);                                                 \
    float rr = qq * dZ, zz = qq * dR;                                         \
    float gn = fmaf(rr, pN, fmaf(xv, wnS_, bnI_));                            \
    float en = exp2hw(fminf(gn, 30.0f));                                      \
    float nn = fmaf(-2.0f, rcpf(1.0f + en), 1.0f);                            \
    h_ = fmaf(zz, h_ - nn, nn);                                               \
    int hq = __float_as_int(fmaf(h_, 127.0f, 12582912.0f));                   \
    *(char*)((wb) + (woff_)) = (char)hq;                                      \
} while (0)

#define DPP3(v_, a_) do {                                                     \
    v_ = a_[0];                                                               \
    v_ = __builtin_amdgcn_update_dpp(v_, a_[1], 0x114, 0xF, 0x2, false);      \
    v_ = __builtin_amdgcn_update_dpp(v_, a_[2], 0x118, 0xF, 0x4, false);      \
    v_ = __builtin_amdgcn_update_dpp(v_, a_[3], 0x11C, 0xF, 0x8, false);      \
} while (0)

#define STEP(rb, wb, t_) do {                                                 \
    intx4 bf0 = *(const intx4*)((rb) + 0 * FRAGB + rbase);                    \
    intx4 bf1 = *(const intx4*)((rb) + 1 * FRAGB + rbase);                    \
    intx4 bf2 = *(const intx4*)((rb) + 2 * FRAGB + rbase);                    \
    float xv = x_s[b * XSTR + (t_)];                                          \
    intx4 cR = {0,0,0,0}, cZ = {0,0,0,0}, cN = {0,0,0,0};                     \
    cR = __builtin_amdgcn_mfma_i32_16x16x64_i8(aAR0, bf0, cR, 0, 0, 0);       \
    cZ = __builtin_amdgcn_mfma_i32_16x16x64_i8(aAZ0, bf0, cZ, 0, 0, 0);       \
    cN = __builtin_amdgcn_mfma_i32_16x16x64_i8(aAN0, bf0, cN, 0, 0, 0);       \
    cR = __builtin_amdgcn_mfma_i32_16x16x64_i8(aAR1, bf1, cR, 0, 0, 0);       \
    cZ = __builtin_amdgcn_mfma_i32_16x16x64_i8(aAZ1, bf1, cZ, 0, 0, 0);       \
    cN = __builtin_amdgcn_mfma_i32_16x16x64_i8(aAN1, bf1, cN, 0, 0, 0);       \
    cR = __builtin_amdgcn_mfma_i32_16x16x64_i8(aAR2, bf2, cR, 0, 0, 0);       \
    cZ = __builtin_amdgcn_mfma_i32_16x16x64_i8(aAZ2, bf2, cZ, 0, 0, 0);       \
    cN = __builtin_amdgcn_mfma_i32_16x16x64_i8(aAN2, bf2, cN, 0, 0, 0);       \
    if (two) {                                                                \
        intx4 eR = {0,0,0,0}, eZ = {0,0,0,0}, eN = {0,0,0,0};                 \
        eR = __builtin_amdgcn_mfma_i32_16x16x64_i8(aBR0, bf0, eR, 0, 0, 0);   \
        eZ = __builtin_amdgcn_mfma_i32_16x16x64_i8(aBZ0, bf0, eZ, 0, 0, 0);   \
        eN = __builtin_amdgcn_mfma_i32_16x16x64_i8(aBN0, bf0, eN, 0, 0, 0);   \
        eR = __builtin_amdgcn_mfma_i32_16x16x64_i8(aBR1, bf1, eR, 0, 0, 0);   \
        eZ = __builtin_amdgcn_mfma_i32_16x16x64_i8(aBZ1, bf1, eZ, 0, 0, 0);   \
        eN = __builtin_amdgcn_mfma_i32_16x16x64_i8(aBN1, bf1, eN, 0, 0, 0);   \
        eR = __builtin_amdgcn_mfma_i32_16x16x64_i8(aBR2, bf2, eR, 0, 0, 0);   \
        eZ = __builtin_amdgcn_mfma_i32_16x16x64_i8(aBZ2, bf2, eZ, 0, 0, 0);   \
        eN = __builtin_amdgcn_mfma_i32_16x16x64_i8(aBN2, bf2, eN, 0, 0, 0);   \
        int vRB, vZB, vNB;                                                    \
        DPP3(vRB, eR); DPP3(vZB, eZ); DPP3(vNB, eN);                          \
        int vRA, vZA, vNA;                                                    \
        DPP3(vRA, cR); DPP3(vZA, cZ); DPP3(vNA, cN);                          \
        GATES(vRA, vZA, vNA, dqRA, dqZA, dqNA, baseRA, baseZA, baseNA,        \
              wrSA, wzSA, wnSA, bnIA, hA, wb, woffA);                         \
        GATES(vRB, vZB, vNB, dqRB, dqZB, dqNB, baseRB, baseZB, baseNB,        \
              wrSB, wzSB, wnSB, bnIB, hB, wb, woffB);                         \
    } else {                                                                  \
        int vRA, vZA, vNA;                                                    \
        DPP3(vRA, cR); DPP3(vZA, cZ); DPP3(vNA, cN);                          \
        GATES(vRA, vZA, vNA, dqRA, dqZA, dqNA, baseRA, baseZA, baseNA,        \
              wrSA, wzSA, wnSA, bnIA, hA, wb, woffA);                         \
    }                                                                         \
    __syncthreads();                                                          \
} while (0)

    char* buf0 = hfr_s;
    char* buf1 = hfr_s + KT3 * FRAGB;
    for (int t = 0; t < T_LEN; t += 2) {
        STEP(buf0, buf1, t);
        STEP(buf1, buf0, t + 1);
    }
#undef STEP
#undef GATES
#undef DPP3

    // ---- final FC: publish h (f32) into x_s (x done), 40 lanes reduce ----
    __syncthreads();
    x_s[b * PST + uA] = hA;                 // uA <= 127 < PST
    if (two) x_s[b * PST + uB] = hB;        // uB <= 191 < PST
    __syncthreads();
    if (tid < BB * 10) {
        int bb = tid / 10, c = tid % 10;
        float acc = b_fc[c];
        for (int k = 0; k < H; ++k)
            acc = fmaf(x_s[bb * PST + k], w_fc[c * H + k], acc);
        out[(b0 + bb) * 10 + c] = acc;
    }
}

extern "C" void kernel_launch(void* const* d_in, const int* in_sizes, int n_in,
                              void* d_out, int out_size, void* d_ws, size_t ws_size,
                              hipStream_t stream) {
    const float* x    = (const float*)d_in[0];
    const float* w_ih = (const float*)d_in[1];
    const float* w_hh = (const float*)d_in[2];
    const float* b_ih = (const float*)d_in[3];
    const float* b_hh = (const float*)d_in[4];
    const float* w_fc = (const float*)d_in[5];
    const float* b_fc = (const float*)d_in[6];
    float* out = (float*)d_out;

    gru_i8<<<NBLK, NTHR, 0, stream>>>(x, w_ih, w_hh, b_ih, b_hh, w_fc, b_fc, out);
}

// Round 19
// 657.782 us; speedup vs baseline: 1.0816x; 1.0816x over previous
//
#include <hip/hip_runtime.h>

#define H 181
#define T_LEN 1024
#define BB 4             // batch rows per block
#define NBLK 256         // 256 * 4 = 1024; one block per CU (LDS-pinned)
#define NTHR 768         // 12 waves, 3 per SIMD (measured-best structure)
#define KT3 3            // k-tiles of 64 -> 192 >= 181
#define FRAGB 1024       // bytes per kt fragment (64 lanes x 16 B)
#define PST 192          // unit stride (wsc, FC)
#define XSTR 1027        // x_s stride (odd -> broadcast reads conflict-free)

typedef __attribute__((ext_vector_type(4))) int intx4;

#define LOG2E 1.4426950408889634f
// Schraudolph exp2 (balanced sawtooth, |rel err| <= ~3%), clamped
#define SCH_C  1064992506.0f
#define SCH_LO 897220352.0f
#define SCH_HI 1182433024.0f

__device__ __forceinline__ float exp2_fast(float g) {
    float s = fmaf(g, 8388608.0f, SCH_C);
    s = fminf(fmaxf(s, SCH_LO), SCH_HI);
    return __uint_as_float((unsigned)s);
}
__device__ __forceinline__ float rcpf(float x)   { return __builtin_amdgcn_rcpf(x); }
__device__ __forceinline__ float exp2hw(float x) { return __builtin_amdgcn_exp2f(x); }

// R26: revert to R20 12-wave structure (671us; R23's 8-wave = 711us
// REGRESSION, and even at 256-reg cap it still spilled WRITE 23MB ->
// spill is beyond source reach). ONE change vs R20: the per-step
// __syncthreads() (which emits s_waitcnt vmcnt(0) lgkmcnt(0) + s_barrier,
// draining the lane-PRIVATE scratch spill traffic every step) is replaced
// by lgkmcnt(0)-only + raw s_barrier. The only cross-wave dependency in
// the loop is ds_write_b8 -> next-step ds_read_b128 (LDS, lgkmcnt);
// scratch (vmcnt) needs no cross-wave visibility. Theory: the per-step
// vmcnt(0) drain serializes ~200-400cy of L2 scratch latency into each
// ~1650cy step = the ~26% stall unaccounted by VALUBusy 45 + MfmaUtil 29,
// and explains why every failed de-spill (R20/R21/R22/R23) left dur flat.
// sched_barrier(0) fences per guide rule #18. Numerics bit-identical.
// Adjudication: dur 520-590 = drain theory confirmed; dur ~670 = scratch
// fully exonerated -> attack gate-VALU chain next.
__device__ __forceinline__ float row_scale(const float* wrow, bool mv) {
    float rm = 0.0f;
    if (mv) for (int k = 0; k < H; ++k) rm = fmaxf(rm, fabsf(wrow[k]));
    return (rm > 1e-30f) ? rm * (1.0f / 127.0f) : 1.0f;
}

__device__ __forceinline__ intx4 build_frag(const float* wrow, float invs,
                                            bool mv, int kt, int q) {
    intx4 frag;
    #pragma unroll
    for (int w = 0; w < 4; ++w) {
        int dw = 0;
        #pragma unroll
        for (int e = 0; e < 4; ++e) {
            int k = kt * 64 + q * 16 + w * 4 + e;
            float v = (mv && k < H) ? wrow[k] * invs : 0.0f;
            v = fminf(fmaxf(rintf(v), -127.0f), 127.0f);
            int iv = (int)v;
            dw |= (iv & 255) << (8 * e);
        }
        frag[w] = dw;
    }
    return frag;
}

__launch_bounds__(NTHR, 3)
__global__ void gru_i8(const float* __restrict__ x,
                       const float* __restrict__ w_ih,
                       const float* __restrict__ w_hh,
                       const float* __restrict__ b_ih,
                       const float* __restrict__ b_hh,
                       const float* __restrict__ w_fc,
                       const float* __restrict__ b_fc,
                       float* __restrict__ out) {
    __shared__ __align__(16) char  hfr_s[2 * KT3 * FRAGB];  // 6 KB i8 h dbuf
    __shared__ __align__(16) float x_s[BB * XSTR];          // 16 KB x; reused for FC
    __shared__ float wsc_s[3 * PST];                        // w_hh row scales
    __shared__ volatile char pad_s[57344];                  // total > 80 KB: pin 1 block/CU

    const int tid  = threadIdx.x;
    const int jt   = tid >> 6;          // wave = unit tile 0..11
    const int lane = tid & 63;
    const int col  = lane & 15;
    const int q    = lane >> 4;
    const int b0   = blockIdx.x * BB;
    if (tid == 0) pad_s[0] = 0;

    // ---- A fragments: per-row int8 w_hh, 3 gates x 3 kt, 9 NAMED regs ----
    const int  mu = jt * 16 + col;
    const bool mv = (mu < H);
    const float* wrowR = w_hh + (size_t)(0 * H + (mv ? mu : 0)) * H;
    const float* wrowZ = w_hh + (size_t)(1 * H + (mv ? mu : 0)) * H;
    const float* wrowN = w_hh + (size_t)(2 * H + (mv ? mu : 0)) * H;
    const float sR = row_scale(wrowR, mv);
    const float sZ = row_scale(wrowZ, mv);
    const float sN = row_scale(wrowN, mv);
    const float iR = 1.0f / sR, iZ = 1.0f / sZ, iN = 1.0f / sN;
    const intx4 afR0 = build_frag(wrowR, iR, mv, 0, q);
    const intx4 afR1 = build_frag(wrowR, iR, mv, 1, q);
    const intx4 afR2 = build_frag(wrowR, iR, mv, 2, q);
    const intx4 afZ0 = build_frag(wrowZ, iZ, mv, 0, q);
    const intx4 afZ1 = build_frag(wrowZ, iZ, mv, 1, q);
    const intx4 afZ2 = build_frag(wrowZ, iZ, mv, 2, q);
    const intx4 afN0 = build_frag(wrowN, iN, mv, 0, q);
    const intx4 afN1 = build_frag(wrowN, iN, mv, 1, q);
    const intx4 afN2 = build_frag(wrowN, iN, mv, 2, q);
    if (q == 0) {
        wsc_s[0 * PST + mu] = sR;
        wsc_s[1 * PST + mu] = sZ;
        wsc_s[2 * PST + mu] = sN;
    }

    // ---- stage x (stride 1027); zero h frag buffers ----
    for (int i = tid; i < BB * T_LEN; i += NTHR) {
        int bb = i >> 10, t = i & 1023;
        x_s[bb * XSTR + t] = x[(size_t)b0 * T_LEN + i];
    }
    {
        int* hz = (int*)hfr_s;
        for (int i = tid; i < 2 * KT3 * FRAGB / 4; i += NTHR) hz[i] = 0;
    }
    __syncthreads();   // wsc_s ready (full barrier; prologue only)

    // ---- dense per-lane identity after DPP redistribute ----
    const int  rr4 = (col >> 2) & 3;       // reg index this lane receives
    const int  b   = col & 3;              // batch
    const int  u   = jt * 16 + q * 4 + rr4;  // unit
    const bool jv  = (u < H);
    const float dqR = -LOG2E * wsc_s[0 * PST + u] * (1.0f / 127.0f);
    const float dqZ = -LOG2E * wsc_s[1 * PST + u] * (1.0f / 127.0f);
    const float dqN =  2.0f * LOG2E * wsc_s[2 * PST + u] * (1.0f / 127.0f);
    const float baseR = jv ? -LOG2E * (b_ih[u] + b_hh[u])             : 0.0f;
    const float baseZ = jv ? -LOG2E * (b_ih[H + u] + b_hh[H + u])     : 0.0f;
    const float baseN = jv ?  2.0f * LOG2E * b_hh[2 * H + u]          : 0.0f;
    const float wrS = jv ? -LOG2E * w_ih[u]                : 0.0f;
    const float wzS = jv ? -LOG2E * w_ih[H + u]            : 0.0f;
    const float wnS = jv ?  2.0f * LOG2E * w_ih[2 * H + u] : 0.0f;
    const float bnI = jv ?  2.0f * LOG2E * b_ih[2 * H + u] : 0.0f;
    // per-lane byte slot in the fragment layout (this lane's unit u, batch b)
    const int wboff8 = (jt >> 2) * FRAGB + (((jt & 3) * 16 + b) * 16) + q * 4 + rr4;
    const int rbase = lane * 16;

    float h = 0.0f;

// LDS-only barrier: ds_write_b8 visibility needs lgkmcnt(0)+s_barrier only;
// scratch spill traffic (vmcnt) is lane-private and floats across steps.
#define LDS_BARRIER() do {                                                    \
    __builtin_amdgcn_sched_barrier(0);                                        \
    asm volatile("s_waitcnt lgkmcnt(0)" ::: "memory");                        \
    __builtin_amdgcn_s_barrier();                                             \
    __builtin_amdgcn_sched_barrier(0);                                        \
} while (0)

// One GRU step: macro (no lambda -> nothing address-taken).
#define STEP(rb, wb, t_) do {                                                 \
    intx4 bf0 = *(const intx4*)((rb) + 0 * FRAGB + rbase);                    \
    intx4 bf1 = *(const intx4*)((rb) + 1 * FRAGB + rbase);                    \
    intx4 bf2 = *(const intx4*)((rb) + 2 * FRAGB + rbase);                    \
    intx4 aR = {0,0,0,0}, aZ = {0,0,0,0}, aN = {0,0,0,0};                     \
    aR = __builtin_amdgcn_mfma_i32_16x16x64_i8(afR0, bf0, aR, 0, 0, 0);       \
    aZ = __builtin_amdgcn_mfma_i32_16x16x64_i8(afZ0, bf0, aZ, 0, 0, 0);       \
    aN = __builtin_amdgcn_mfma_i32_16x16x64_i8(afN0, bf0, aN, 0, 0, 0);       \
    aR = __builtin_amdgcn_mfma_i32_16x16x64_i8(afR1, bf1, aR, 0, 0, 0);       \
    aZ = __builtin_amdgcn_mfma_i32_16x16x64_i8(afZ1, bf1, aZ, 0, 0, 0);       \
    aN = __builtin_amdgcn_mfma_i32_16x16x64_i8(afN1, bf1, aN, 0, 0, 0);       \
    aR = __builtin_amdgcn_mfma_i32_16x16x64_i8(afR2, bf2, aR, 0, 0, 0);       \
    aZ = __builtin_amdgcn_mfma_i32_16x16x64_i8(afZ2, bf2, aZ, 0, 0, 0);       \
    aN = __builtin_amdgcn_mfma_i32_16x16x64_i8(afN2, bf2, aN, 0, 0, 0);       \
    int vR = aR[0], vZ = aZ[0], vN = aN[0];                                   \
    vR = __builtin_amdgcn_update_dpp(vR, aR[1], 0x114, 0xF, 0x2, false);      \
    vR = __builtin_amdgcn_update_dpp(vR, aR[2], 0x118, 0xF, 0x4, false);      \
    vR = __builtin_amdgcn_update_dpp(vR, aR[3], 0x11C, 0xF, 0x8, false);      \
    vZ = __builtin_amdgcn_update_dpp(vZ, aZ[1], 0x114, 0xF, 0x2, false);      \
    vZ = __builtin_amdgcn_update_dpp(vZ, aZ[2], 0x118, 0xF, 0x4, false);      \
    vZ = __builtin_amdgcn_update_dpp(vZ, aZ[3], 0x11C, 0xF, 0x8, false);      \
    vN = __builtin_amdgcn_update_dpp(vN, aN[1], 0x114, 0xF, 0x2, false);      \
    vN = __builtin_amdgcn_update_dpp(vN, aN[2], 0x118, 0xF, 0x4, false);      \
    vN = __builtin_amdgcn_update_dpp(vN, aN[3], 0x11C, 0xF, 0x8, false);      \
    float pR = fmaf((float)vR, dqR, baseR);                                   \
    float pZ = fmaf((float)vZ, dqZ, baseZ);                                   \
    float pN = fmaf((float)vN, dqN, baseN);                                   \
    float xv = x_s[b * XSTR + (t_)];                                          \
    float er = exp2_fast(fmaf(xv, wrS, pR));                                  \
    float ez = exp2hw(fminf(fmaf(xv, wzS, pZ), 14.0f));                       \
    float dR = 1.0f + er, dZ = 1.0f + ez;                                     \
    float qq = rcpf(dR * dZ);                                                 \
    float rr = qq * dZ, zz = qq * dR;                                         \
    float gn = fmaf(rr, pN, fmaf(xv, wnS, bnI));                              \
    float en = exp2hw(fminf(gn, 30.0f));                                      \
    float nn = fmaf(-2.0f, rcpf(1.0f + en), 1.0f);                            \
    h = fmaf(zz, h - nn, nn);                                                 \
    int hq = __float_as_int(fmaf(h, 127.0f, 12582912.0f));                    \
    *(char*)((wb) + wboff8) = (char)hq;                                       \
    LDS_BARRIER();                                                            \
} while (0)

    char* buf0 = hfr_s;
    char* buf1 = hfr_s + KT3 * FRAGB;
    for (int t = 0; t < T_LEN; t += 2) {
        STEP(buf0, buf1, t);
        STEP(buf1, buf0, t + 1);
    }
#undef STEP
#undef LDS_BARRIER

    // ---- final FC: publish h (f32) into x_s (x done), 40 lanes reduce ----
    __syncthreads();
    if (u < PST) x_s[b * PST + u] = h;
    __syncthreads();
    if (tid < BB * 10) {
        int bb = tid / 10, c = tid % 10;
        float acc = b_fc[c];
        for (int k = 0; k < H; ++k)
            acc = fmaf(x_s[bb * PST + k], w_fc[c * H + k], acc);
        out[(b0 + bb) * 10 + c] = acc;
    }
}

extern "C" void kernel_launch(void* const* d_in, const int* in_sizes, int n_in,
                              void* d_out, int out_size, void* d_ws, size_t ws_size,
                              hipStream_t stream) {
    const float* x    = (const float*)d_in[0];
    const float* w_ih = (const float*)d_in[1];
    const float* w_hh = (const float*)d_in[2];
    const float* b_ih = (const float*)d_in[3];
    const float* b_hh = (const float*)d_in[4];
    const float* w_fc = (const float*)d_in[5];
    const float* b_fc = (const float*)d_in[6];
    float* out = (float*)d_out;

    gru_i8<<<NBLK, NTHR, 0, stream>>>(x, w_ih, w_hh, b_ih, b_hh, w_fc, b_fc, out);
}